// Round 9
// baseline (152.227 us; speedup 1.0000x reference)
//
#include <hip/hip_runtime.h>
#include <cstdint>

typedef unsigned short ushortT;
typedef __attribute__((ext_vector_type(8))) short short8;      // 8 bf16 = 4 VGPRs (MFMA A/B frag)
typedef __attribute__((ext_vector_type(8))) unsigned short ushort8v;
typedef __attribute__((ext_vector_type(4))) float float4v;

#define ATT_SCALE 0.17677669529663687f   // 32^-0.5

__device__ inline float bf2f(unsigned short u) {
    union { unsigned int i; float f; } x; x.i = ((unsigned int)u) << 16; return x.f;
}
__device__ inline unsigned short f2bf(float f) {
    union { float f; unsigned int i; } x; x.f = f;
    unsigned int i = x.i;
    i += 0x7fffu + ((i >> 16) & 1u);      // RNE
    return (unsigned short)(i >> 16);
}

__device__ inline void gld_lds16(const ushortT* g, ushortT* l) {
    // async global->LDS, 16B/lane; LDS dest = wave-uniform base + lane*16
    __builtin_amdgcn_global_load_lds((const __attribute__((address_space(1))) void*)g,
                                     (__attribute__((address_space(3))) void*)l, 16, 0, 0);
}

// ---------------------------------------------------------------------------
// Transpose+convert (B, 256, 4096) fp32 -> (B, 4096, 256) bf16, AND (in the
// first 1028 blocks) convert weights->bf16 / biases->fp32 (folded kernel).
// grid (4,64,8), block 256. xT lives in d_out (dead until the final
// projection GEMM overwrites every element).  (R1-exact.)
// ---------------------------------------------------------------------------
__global__ __launch_bounds__(256) void transpose_cp(const float* __restrict__ x,
                                                    ushortT* __restrict__ xT,
                                                    const float* __restrict__ w_qkv,
                                                    const float* __restrict__ w_proj,
                                                    const float* __restrict__ b_qkv,
                                                    const float* __restrict__ b_proj,
                                                    ushortT* __restrict__ wqkvB,
                                                    ushortT* __restrict__ wprojB,
                                                    float* __restrict__ bqF,
                                                    float* __restrict__ bpF) {
    __shared__ __align__(16) ushortT tile[64][65];
    const int b  = blockIdx.z;
    const int c0 = blockIdx.x * 64;
    const int p0 = blockIdx.y * 64;
    const int t  = threadIdx.x;

    // folded param conversion (1 MB total, spread over 1028 blocks)
    {
        int flat = blockIdx.x + 4 * blockIdx.y + 256 * blockIdx.z;   // 0..2047
        if (flat < 1028) {
            int i = flat * 256 + t;
            if (i < 196608) {
                wqkvB[i] = f2bf(w_qkv[i]);
            } else if (i < 262144) {
                wprojB[i - 196608] = f2bf(w_proj[i - 196608]);
            } else if (i < 262912) {
                bqF[i - 262144] = b_qkv[i - 262144];
            } else if (i < 263168) {
                bpF[i - 262912] = b_proj[i - 262912];
            }
        }
    }

    const float* xb = x + (size_t)b * 256 * 4096;
#pragma unroll
    for (int it = 0; it < 4; it++) {
        int id  = t + it * 256;          // 0..1023
        int row = id >> 4;               // c row 0..63
        int c4  = (id & 15) * 4;         // p chunk of 4 floats
        float4 v = *(const float4*)(xb + (size_t)(c0 + row) * 4096 + p0 + c4);
        tile[row][c4 + 0] = f2bf(v.x);
        tile[row][c4 + 1] = f2bf(v.y);
        tile[row][c4 + 2] = f2bf(v.z);
        tile[row][c4 + 3] = f2bf(v.w);
    }
    __syncthreads();
    ushortT* xTb = xT + (size_t)b * 4096 * 256;
#pragma unroll
    for (int it = 0; it < 2; it++) {
        int id   = t + it * 256;             // 0..511
        int prow = id >> 3;                  // p row 0..63
        int cc   = (id & 7) * 8;             // c chunk
        ushort8v v;
#pragma unroll
        for (int j = 0; j < 8; j++) v[j] = tile[cc + j][prow];
        *(ushort8v*)(xTb + (size_t)(p0 + prow) * 256 + c0 + cc) = v;
    }
}

// ---------------------------------------------------------------------------
// GEMM  D[m][n] = sum_k A[m][k] * Bt[n][k]  + bias   (bf16 in, fp32 acc)
// R9: tile 64x64 (R8 was 64x128; R1 128x128). SAME BK=64 single-buffer
// drain loop + XOR-swizzled LDS layout (every sync-structure edit measured
// a regression: R3 +7.4, R4 +4.9, R5 +5.6, R6 +27 (VGPR blowup), R7 +46
// (forced bounds -> spill)). The one measured-WIN lever (R1, R8): smaller
// independent blocks -> more co-resident blocks/CU -> one block's
// vmcnt-drain convoy is covered by other blocks' MFMA phases.
//   per block: acc 2x2 (16 VGPR, ~60-70 total, no forced bounds),
//   LDS 16 KB (A 8K + B 8K), 4 gld_lds/thread/stage, 8 MFMA/wave/stage.
//   G1: 6144 blocks, ~8 resident/CU (was 6). B = weights, L2-resident ->
//       extra B re-reads free; A read once. No HBM delta.
//   G2: 2048 blocks, ~8 resident/CU (was 4). mode-1 swizzle maps XCD r ->
//       batch r, so each XCD's y slice is 2.1 MB (L2-fit); the 4 m-sharers
//       of a y-panel are same-XCD -> L2 hits. No HBM delta.
// LDS layout: row r (stride 64 elems = 128 B), 8 chunk-slots of 8 bf16;
// content at slot s = global chunk (s ^ (r&7)) -> frag reads at
// slot (k8 ^ (r&7)) give 2-way bank aliasing (free).
// Accumulation order per output element IDENTICAL to R1/R8 -> bit-identical.
// ---------------------------------------------------------------------------
__global__ __launch_bounds__(256) void gemm_bt(const ushortT* __restrict__ A,
                                               const ushortT* __restrict__ Bt, long long sBb,
                                               int ldb, int bHeadMajor,
                                               void* __restrict__ D, long long sDb,
                                               int ldd, int dHeadMajor, int outF32,
                                               const float* __restrict__ bias, int biasAlongM,
                                               int K, int swizzleMode) {
    __shared__ __align__(16) ushortT pool[8192];    // 16 KB: [A(8K)|B(8K)] / epilogue

    int mIdx, nIdx, bz;
    {
        int id = blockIdx.x;
        int r  = id & 7;                // XCD
        int j  = id >> 3;
        if (swizzleMode == 0) {
            mIdx = r * 64 + j / 12;     // 12 n-blocks sharing an A-panel -> same XCD
            nIdx = j % 12;
            bz   = 0;
        } else {
            mIdx = j & 3;               // 4 m-blocks sharing a y-panel -> same XCD
            int pp = r * 64 + (j >> 2); // 0..511
            bz   = pp >> 6;             // == r: XCD r handles batch r (y L2-fit)
            nIdx = pp & 63;
        }
    }
    const int n0 = nIdx * 64;
    const int m0 = mIdx * 64;
    Bt += (size_t)bz * sBb;

    const int t    = threadIdx.x;
    const int wv   = t >> 6;
    const int lane = t & 63;
    const int lm   = lane & 15;
    const int quad = lane >> 4;
    const int wm   = wv & 1;     // wave's 32-row quadrant (m)
    const int wn   = wv >> 1;    // wave's 32-col quadrant (n)

    ushortT* Als = pool;            // 64 rows x 64 elems (8 KB)
    ushortT* Bls = pool + 4096;     // 64 rows x 64 elems (8 KB)

    float4v acc[2][2];
#pragma unroll
    for (int i = 0; i < 2; i++)
#pragma unroll
        for (int j = 0; j < 2; j++) { float4v z = {0.f, 0.f, 0.f, 0.f}; acc[i][j] = z; }

    const int nkt = K >> 6;          // BK=64
    for (int kt = 0; kt < nkt; ++kt) {
        __syncthreads();   // previous stage's LDS reads complete before overwrite
        // stage A+B: 512 16B-chunks each; per wave 128 chunks (2 iters) each
#pragma unroll
        for (int j = 0; j < 2; j++) {
            int cid = wv * 128 + j * 64 + lane;   // chunk id in [0,512)
            int row = cid >> 3;                   // tile row (8 chunks of 8 bf16)
            int s   = cid & 7;                    // physical slot
            int gc  = s ^ (row & 7);              // global chunk (perm within row)
            gld_lds16(A + (size_t)(m0 + row) * K + kt * 64 + gc * 8,
                      Als + (size_t)cid * 8);
            const ushortT* gb = bHeadMajor
                ? Bt + ((size_t)(kt * 2 + (gc >> 2)) * 32768 + (n0 + row)) * 32 + (gc & 3) * 8
                : Bt + (size_t)(n0 + row) * ldb + kt * 64 + gc * 8;
            gld_lds16(gb, Bls + (size_t)cid * 8);
        }
        asm volatile("s_waitcnt vmcnt(0)" ::: "memory");
        __syncthreads();

#pragma unroll
        for (int g = 0; g < 2; g++) {            // k-group: k = g*32 .. g*32+31
            short8 af[2], bfr[2];
#pragma unroll
            for (int i = 0; i < 2; i++) {
                int r = wm * 32 + i * 16 + lm;
                int slot = (g * 4 + quad) ^ (r & 7);
                af[i] = *(const short8*)&Als[r * 64 + slot * 8];
            }
#pragma unroll
            for (int j = 0; j < 2; j++) {
                int r = wn * 32 + j * 16 + lm;
                int slot = (g * 4 + quad) ^ (r & 7);
                bfr[j] = *(const short8*)&Bls[r * 64 + slot * 8];
            }
#pragma unroll
            for (int i = 0; i < 2; i++)
#pragma unroll
                for (int j = 0; j < 2; j++)
                    acc[i][j] = __builtin_amdgcn_mfma_f32_16x16x32_bf16(af[i], bfr[j], acc[i][j], 0, 0, 0);
        }
    }

    // epilogue: C/D layout col = lane&15, row = quad*4 + reg
    if (dHeadMajor) {
        __syncthreads();   // all frag reads done before pool overwrite
        // stage 64x64 bf16 (8 KB) with chunk swizzle (c>>3)^(r&7)
#pragma unroll
        for (int i = 0; i < 2; i++) {
#pragma unroll
            for (int j = 0; j < 2; j++) {
                int c = wn * 32 + j * 16 + lm;
#pragma unroll
                for (int rg = 0; rg < 4; rg++) {
                    int r = wm * 32 + i * 16 + quad * 4 + rg;   // 0..63
                    float v = acc[i][j][rg] + bias[biasAlongM ? (m0 + r) : (n0 + c)];
                    int chunk = (c >> 3) ^ (r & 7);
                    pool[r * 64 + chunk * 8 + (c & 7)] = f2bf(v);
                }
            }
        }
        __syncthreads();
        ushortT* Dh = (ushortT*)D + (size_t)bz * sDb;
#pragma unroll
        for (int g = 0; g < 2; g++) {       // two 32-channel groups
            ushortT* base = Dh + ((size_t)((n0 >> 5) + g) * 32768 + m0) * 32;
            int r  = t >> 2;                // 0..63
            int cb = t & 3;                 // 8-chunk within 32-channel group
            int pch = (g * 4 + cb) ^ (r & 7);
            ushort8v v = *(const ushort8v*)&pool[r * 64 + pch * 8];
            *(ushort8v*)(base + r * 32 + cb * 8) = v;
        }
    } else if (outF32) {
        // single pass: stage 64x64 fp32 (16 KB) with +4r column rotation,
        // then fully-coalesced float4 stores.
        float* poolF = (float*)pool;
        float* Df = (float*)D + (size_t)bz * sDb;
        __syncthreads();   // tile reads complete before pool overwrite
#pragma unroll
        for (int i = 0; i < 2; i++) {
#pragma unroll
            for (int j = 0; j < 2; j++) {
                int c = wn * 32 + j * 16 + lm;                   // 0..63
#pragma unroll
                for (int rg = 0; rg < 4; rg++) {
                    int r64 = wm * 32 + i * 16 + quad * 4 + rg;  // 0..63
                    float v = acc[i][j][rg] +
                              bias[biasAlongM ? (m0 + r64) : (n0 + c)];
                    int phys = (c + 4 * r64) & 63;               // rotation: bank spread
                    poolF[r64 * 64 + phys] = v;
                }
            }
        }
        __syncthreads();
#pragma unroll
        for (int it = 0; it < 4; it++) {
            int id  = it * 256 + t;          // 0..1023
            int r64 = id >> 4;               // 0..63
            int c   = (id & 15) * 4;         // logical float4 col
            int phys = (c + 4 * r64) & 63;   // multiple of 4, max 60 -> no wrap
            float4v v = *(const float4v*)&poolF[r64 * 64 + phys];
            *(float4v*)&Df[(size_t)(m0 + r64) * ldd + n0 + c] = v;
        }
    } else {
        ushortT* Dh = (ushortT*)D + (size_t)bz * sDb;
#pragma unroll
        for (int i = 0; i < 2; i++) {
            int r0 = m0 + wm * 32 + i * 16 + quad * 4;
#pragma unroll
            for (int j = 0; j < 2; j++) {
                int c = n0 + wn * 32 + j * 16 + lm;
#pragma unroll
                for (int rg = 0; rg < 4; rg++) {
                    int r = r0 + rg;
                    float v = acc[i][j][rg] + bias[biasAlongM ? r : c];
                    Dh[(size_t)r * ldd + c] = f2bf(v);
                }
            }
        }
    }
}

// ---------------------------------------------------------------------------
// Multi-dilated 3x3 local attention, IN-PLACE on HEAD-MAJOR bf16 qkv:
// qkv[(part*8+hd)*32768 + bp][32], part in {q,k,v}.  (R1-exact version.)
// FOUR lanes per pixel (channel quarter each): 16384 waves, 8 waves/SIMD.
// A 4-lane group covers one pixel's contiguous 64B of k/v -> a wave reads a
// contiguous 1 KB segment per neighbor. Logit dot reduced across the quad
// with 2x __shfl_xor; softmax recomputed redundantly in all 4 lanes.
// OOB: logit exactly 0 stays in the denominator, v = 0. Thread writes only
// its own q quarter -> race-free.
// ---------------------------------------------------------------------------
__global__ __launch_bounds__(256, 8) void attn_k(ushortT* qkv) {
    const int gt      = blockIdx.x * 256 + threadIdx.x;
    const int quarter = gt & 3;          // channel quarter 0..3
    const int pix     = gt >> 2;         // 0..262143
    const int hd      = pix >> 15;       // 0..7  (32768 pixels per head)
    const int rem     = pix & 32767;
    const int b       = rem >> 12;
    const int p       = rem & 4095;      // wave covers 16 consecutive p -> h uniform
    const int h       = p >> 6;
    const int w       = p & 63;
    const int dil     = (hd & 3) + 1;    // DILATIONS = [1,2,3,4]
    const int c0      = quarter * 8;

    ushortT*       qp    = qkv + ((size_t)hd * 32768 + (size_t)b * 4096 + p) * 32 + c0;
    const ushortT* kbase = qkv + ((size_t)(8  + hd) * 32768 + (size_t)b * 4096) * 32 + c0;
    const ushortT* vbase = qkv + ((size_t)(16 + hd) * 32768 + (size_t)b * 4096) * 32 + c0;

    float q[8];
    {
        ushort8v v = *(const ushort8v*)qp;
#pragma unroll
        for (int j = 0; j < 8; j++) q[j] = bf2f(v[j]);
    }

    float lgt[9];
    int   nb[9];
    unsigned vmask = 0;
#pragma unroll
    for (int ii = 0; ii < 3; ii++) {
#pragma unroll
        for (int jj = 0; jj < 3; jj++) {
            int idx = ii * 3 + jj;
            int hh = h + (ii - 1) * dil;   // wave-uniform
            int ww = w + (jj - 1) * dil;   // group-uniform (same pixel in all 4 lanes)
            bool ok = ((unsigned)hh < 64u) && ((unsigned)ww < 64u);
            int pp = (hh << 6) + ww;
            nb[idx] = pp;
            float l = 0.f;                 // OOB: k is zero-padded -> logit exactly 0
            if (ok) {
                vmask |= (1u << idx);
                ushort8v v = *(const ushort8v*)(kbase + (size_t)pp * 32);
#pragma unroll
                for (int j = 0; j < 8; j++) l += q[j] * bf2f(v[j]);
            }
            lgt[idx] = l;
        }
    }
    // quad reduce: lanes 4i..4i+3 hold partial dots of the same pixel.
    // OOB groups reduce 0+0+0+0 = 0 -> semantics preserved.
#pragma unroll
    for (int i = 0; i < 9; i++) {
        float l = lgt[i];
        l += __shfl_xor(l, 1);
        l += __shfl_xor(l, 2);
        lgt[i] = l * ATT_SCALE;
    }

    float mx = lgt[0];
#pragma unroll
    for (int i = 1; i < 9; i++) mx = fmaxf(mx, lgt[i]);
    float e[9], s = 0.f;
#pragma unroll
    for (int i = 0; i < 9; i++) { e[i] = __expf(lgt[i] - mx); s += e[i]; }
    const float inv = 1.f / s;

    float acc[8];
#pragma unroll
    for (int d = 0; d < 8; d++) acc[d] = 0.f;
#pragma unroll
    for (int idx = 0; idx < 9; idx++) {
        if ((vmask >> idx) & 1u) {        // OOB: v = 0, contributes nothing (e[idx] stays in s)
            float pj = e[idx] * inv;
            ushort8v v = *(const ushort8v*)(vbase + (size_t)nb[idx] * 32);
#pragma unroll
            for (int j = 0; j < 8; j++) acc[j] += pj * bf2f(v[j]);
        }
    }

    {
        ushort8v v;
#pragma unroll
        for (int j = 0; j < 8; j++) v[j] = f2bf(acc[j]);
        *(ushort8v*)qp = v;               // overwrite own q quarter
    }
}

// ---------------------------------------------------------------------------
extern "C" void kernel_launch(void* const* d_in, const int* in_sizes, int n_in,
                              void* d_out, int out_size, void* d_ws, size_t ws_size,
                              hipStream_t stream) {
    const float* x      = (const float*)d_in[0];  // (8,256,64,64) fp32
    const float* w_qkv  = (const float*)d_in[1];  // (768,256)
    const float* b_qkv  = (const float*)d_in[2];  // (768,)
    const float* w_proj = (const float*)d_in[3];  // (256,256)
    const float* b_proj = (const float*)d_in[4];  // (256,)

    // ws layout (256B-aligned): bqF | bpF | wqkvB | wprojB | qkv(head-major)
    char* ws = (char*)d_ws;
    float*   bqF    = (float*)(ws + 256);              // 768 f32
    float*   bpF    = (float*)(ws + 3328);             // 256 f32
    ushortT* wqkvB  = (ushortT*)(ws + 4352);           // 196608 bf16
    ushortT* wprojB = (ushortT*)(ws + 397568);         // 65536 bf16
    ushortT* qkv    = (ushortT*)(ws + 528640);         // 24 x 32768 x 32 bf16 = 48 MiB
    ushortT* xT     = (ushortT*)d_out;                 // (32768,256) bf16 scratch in d_out;
                                                       // fully overwritten by the final GEMM

    // 1) x (B,C,P) -> xT (B,P,C) bf16  +  folded param conversion
    transpose_cp<<<dim3(4, 64, 8), 256, 0, stream>>>(x, xT, w_qkv, w_proj, b_qkv, b_proj,
                                                     wqkvB, wprojB, bqF, bpF);

    // 2) qkv head-major = xT(32768,256) @ w_qkv^T + b_qkv   (bias along n)
    //    64x64 tiles: 6144 blocks, ~8 resident/CU (16 KB LDS, ~64 VGPR).
    //    XCD swizzle mode 0 (12 n-blocks per A-panel share an XCD).
    gemm_bt<<<dim3(6144), 256, 0, stream>>>(xT, wqkvB, 0, 256, 0,
                                            qkv, 0, 0, 1, 0,
                                            bqF, 0, 256, 0);

    // 3) attention in-place on head-major qkv (y overwrites q quarters)
    //    4 lanes per pixel: 1,048,576 threads = 16384 waves (8/SIMD resident)
    attn_k<<<dim3(4096), 256, 0, stream>>>(qkv);

    // 4) out(b,256,4096) fp32 = w_proj @ y(b)^T + b_proj  (bias along m)
    //    64x64 tiles: 2048 blocks, ~8 resident/CU (was 4). XCD swizzle
    //    mode 1: XCD r <-> batch r (y slice 2.1 MB, L2-fit).
    gemm_bt<<<dim3(2048), 256, 0, stream>>>(wprojB, qkv, (long long)4096 * 32, 0, 1,
                                            d_out, (long long)256 * 4096, 4096, 0, 1,
                                            bpF, 1, 256, 1);
}

// Round 10
// 146.316 us; speedup vs baseline: 1.0404x; 1.0404x over previous
//
#include <hip/hip_runtime.h>
#include <cstdint>

typedef unsigned short ushortT;
typedef __attribute__((ext_vector_type(8))) short short8;      // 8 bf16 = 4 VGPRs (MFMA A/B frag)
typedef __attribute__((ext_vector_type(8))) unsigned short ushort8v;
typedef __attribute__((ext_vector_type(4))) float float4v;

#define ATT_SCALE 0.17677669529663687f   // 32^-0.5

__device__ inline float bf2f(unsigned short u) {
    union { unsigned int i; float f; } x; x.i = ((unsigned int)u) << 16; return x.f;
}
__device__ inline unsigned short f2bf(float f) {
    union { float f; unsigned int i; } x; x.f = f;
    unsigned int i = x.i;
    i += 0x7fffu + ((i >> 16) & 1u);      // RNE
    return (unsigned short)(i >> 16);
}

__device__ inline void gld_lds16(const ushortT* g, ushortT* l) {
    // async global->LDS, 16B/lane; LDS dest = wave-uniform base + lane*16
    __builtin_amdgcn_global_load_lds((const __attribute__((address_space(1))) void*)g,
                                     (__attribute__((address_space(3))) void*)l, 16, 0, 0);
}

// ---------------------------------------------------------------------------
// Transpose+convert (B, 256, 4096) fp32 -> (B, 4096, 256) bf16, AND (in the
// first 1028 blocks) convert weights->bf16 / biases->fp32 (folded kernel).
// grid (4,64,8), block 256. xT lives in d_out (dead until the final
// projection GEMM overwrites every element).  (R1-exact.)
// ---------------------------------------------------------------------------
__global__ __launch_bounds__(256) void transpose_cp(const float* __restrict__ x,
                                                    ushortT* __restrict__ xT,
                                                    const float* __restrict__ w_qkv,
                                                    const float* __restrict__ w_proj,
                                                    const float* __restrict__ b_qkv,
                                                    const float* __restrict__ b_proj,
                                                    ushortT* __restrict__ wqkvB,
                                                    ushortT* __restrict__ wprojB,
                                                    float* __restrict__ bqF,
                                                    float* __restrict__ bpF) {
    __shared__ __align__(16) ushortT tile[64][65];
    const int b  = blockIdx.z;
    const int c0 = blockIdx.x * 64;
    const int p0 = blockIdx.y * 64;
    const int t  = threadIdx.x;

    // folded param conversion (1 MB total, spread over 1028 blocks)
    {
        int flat = blockIdx.x + 4 * blockIdx.y + 256 * blockIdx.z;   // 0..2047
        if (flat < 1028) {
            int i = flat * 256 + t;
            if (i < 196608) {
                wqkvB[i] = f2bf(w_qkv[i]);
            } else if (i < 262144) {
                wprojB[i - 196608] = f2bf(w_proj[i - 196608]);
            } else if (i < 262912) {
                bqF[i - 262144] = b_qkv[i - 262144];
            } else if (i < 263168) {
                bpF[i - 262912] = b_proj[i - 262912];
            }
        }
    }

    const float* xb = x + (size_t)b * 256 * 4096;
#pragma unroll
    for (int it = 0; it < 4; it++) {
        int id  = t + it * 256;          // 0..1023
        int row = id >> 4;               // c row 0..63
        int c4  = (id & 15) * 4;         // p chunk of 4 floats
        float4 v = *(const float4*)(xb + (size_t)(c0 + row) * 4096 + p0 + c4);
        tile[row][c4 + 0] = f2bf(v.x);
        tile[row][c4 + 1] = f2bf(v.y);
        tile[row][c4 + 2] = f2bf(v.z);
        tile[row][c4 + 3] = f2bf(v.w);
    }
    __syncthreads();
    ushortT* xTb = xT + (size_t)b * 4096 * 256;
#pragma unroll
    for (int it = 0; it < 2; it++) {
        int id   = t + it * 256;             // 0..511
        int prow = id >> 3;                  // p row 0..63
        int cc   = (id & 7) * 8;             // c chunk
        ushort8v v;
#pragma unroll
        for (int j = 0; j < 8; j++) v[j] = tile[cc + j][prow];
        *(ushort8v*)(xTb + (size_t)(p0 + prow) * 256 + c0 + cc) = v;
    }
}

// ---------------------------------------------------------------------------
// GEMM  D[m][n] = sum_k A[m][k] * Bt[n][k]  + bias   (bf16 in, fp32 acc)
// R8-EXACT (measured session best, 149.7us): tile 64x128, BK=64 single-
// buffer drain loop, XOR-swizzled LDS. Tile-size curve measured: 128x128 =
// 153.1, 64x128 = 149.7, 64x64 = 152.2 -> 64x128 is the optimum. Every
// sync-structure edit regressed (R3 +7.4, R4 +4.9, R5 +5.6, R6 +27 VGPR
// blowup, R7 +46 forced-bounds spill). GEMMs are FROZEN in this form.
//   per block: acc 2x4 (~80 VGPR, no forced bounds), LDS 24 KB,
//   6 gld_lds/thread/stage, 16 MFMA/wave/stage.
//   G1: 3072 blocks, ~6 resident/CU.  G2: 1024 blocks, 4 resident/CU.
// LDS layout: row r (stride 64 elems = 128 B), 8 chunk-slots of 8 bf16;
// content at slot s = global chunk (s ^ (r&7)) -> frag reads at
// slot (k8 ^ (r&7)) give 2-way bank aliasing (free).
// XCD swizzle: mode 0 -> 6 n-blocks sharing an A-panel on one XCD;
// mode 1 -> 4 m-blocks sharing a y-panel (bz,n) on one XCD.
// ---------------------------------------------------------------------------
__global__ __launch_bounds__(256) void gemm_bt(const ushortT* __restrict__ A,
                                               const ushortT* __restrict__ Bt, long long sBb,
                                               int ldb, int bHeadMajor,
                                               void* __restrict__ D, long long sDb,
                                               int ldd, int dHeadMajor, int outF32,
                                               const float* __restrict__ bias, int biasAlongM,
                                               int K, int swizzleMode) {
    __shared__ __align__(16) ushortT pool[12288];   // 24 KB: [A(8K)|B(16K)] / epilogue

    int mIdx, nIdx, bz;
    {
        int id = blockIdx.x;
        int r  = id & 7;                // XCD
        int j  = id >> 3;
        if (swizzleMode == 0) {
            mIdx = r * 64 + j / 6;      // 6 n-blocks sharing an A-panel -> same XCD
            nIdx = j % 6;
            bz   = 0;
        } else {
            mIdx = j & 3;               // 4 m-blocks sharing a y-panel -> same XCD
            int pp = r * 32 + (j >> 2); // 0..255
            bz   = pp >> 5;
            nIdx = pp & 31;
        }
    }
    const int n0 = nIdx * 128;
    const int m0 = mIdx * 64;
    Bt += (size_t)bz * sBb;

    const int t    = threadIdx.x;
    const int wv   = t >> 6;
    const int lane = t & 63;
    const int lm   = lane & 15;
    const int quad = lane >> 4;
    const int wm   = wv & 1;     // wave's 32-row half (m)
    const int wn   = wv >> 1;    // wave's 64-col half (n)

    ushortT* Als = pool;            // 64 rows x 64 elems (8 KB)
    ushortT* Bls = pool + 4096;     // 128 rows x 64 elems (16 KB)

    float4v acc[2][4];
#pragma unroll
    for (int i = 0; i < 2; i++)
#pragma unroll
        for (int j = 0; j < 4; j++) { float4v z = {0.f, 0.f, 0.f, 0.f}; acc[i][j] = z; }

    const int nkt = K >> 6;          // BK=64
    for (int kt = 0; kt < nkt; ++kt) {
        __syncthreads();   // previous stage's LDS reads complete before overwrite
        // stage A: 512 16B-chunks (64 rows x 8); each wave 128 chunks (2 iters)
#pragma unroll
        for (int j = 0; j < 2; j++) {
            int cid = wv * 128 + j * 64 + lane;   // chunk id in [0,512)
            int row = cid >> 3;
            int s   = cid & 7;
            int gc  = s ^ (row & 7);
            gld_lds16(A + (size_t)(m0 + row) * K + kt * 64 + gc * 8,
                      Als + (size_t)cid * 8);
        }
        // stage B: 1024 16B-chunks (128 rows x 8); each wave 256 chunks (4 iters)
#pragma unroll
        for (int j = 0; j < 4; j++) {
            int cid = wv * 256 + j * 64 + lane;   // chunk id in [0,1024)
            int row = cid >> 3;
            int s   = cid & 7;
            int gc  = s ^ (row & 7);
            const ushortT* gb = bHeadMajor
                ? Bt + ((size_t)(kt * 2 + (gc >> 2)) * 32768 + (n0 + row)) * 32 + (gc & 3) * 8
                : Bt + (size_t)(n0 + row) * ldb + kt * 64 + gc * 8;
            gld_lds16(gb, Bls + (size_t)cid * 8);
        }
        asm volatile("s_waitcnt vmcnt(0)" ::: "memory");
        __syncthreads();

#pragma unroll
        for (int g = 0; g < 2; g++) {            // k-group: k = g*32 .. g*32+31
            short8 af[2], bfr[4];
#pragma unroll
            for (int i = 0; i < 2; i++) {
                int r = wm * 32 + i * 16 + lm;
                int slot = (g * 4 + quad) ^ (r & 7);
                af[i] = *(const short8*)&Als[r * 64 + slot * 8];
            }
#pragma unroll
            for (int j = 0; j < 4; j++) {
                int r = wn * 64 + j * 16 + lm;
                int slot = (g * 4 + quad) ^ (r & 7);
                bfr[j] = *(const short8*)&Bls[r * 64 + slot * 8];
            }
#pragma unroll
            for (int i = 0; i < 2; i++)
#pragma unroll
                for (int j = 0; j < 4; j++)
                    acc[i][j] = __builtin_amdgcn_mfma_f32_16x16x32_bf16(af[i], bfr[j], acc[i][j], 0, 0, 0);
        }
    }

    // epilogue: C/D layout col = lane&15, row = quad*4 + reg
    if (dHeadMajor) {
        __syncthreads();   // all frag reads done before pool overwrite
#pragma unroll
        for (int i = 0; i < 2; i++) {
#pragma unroll
            for (int j = 0; j < 4; j++) {
                int c = wn * 64 + j * 16 + lm;
#pragma unroll
                for (int rg = 0; rg < 4; rg++) {
                    int r = wm * 32 + i * 16 + quad * 4 + rg;   // 0..63
                    float v = acc[i][j][rg] + bias[biasAlongM ? (m0 + r) : (n0 + c)];
                    int chunk = (c >> 3) ^ (r & 7);
                    pool[r * 128 + chunk * 8 + (c & 7)] = f2bf(v);   // 16 KB used
                }
            }
        }
        __syncthreads();
        ushortT* Dh = (ushortT*)D + (size_t)bz * sDb;
#pragma unroll
        for (int g = 0; g < 4; g++) {
            ushortT* base = Dh + ((size_t)((n0 >> 5) + g) * 32768 + m0) * 32;
            int r  = t >> 2;                // 0..63
            int cb = t & 3;                 // 8-chunk within 32-channel group
            int pch = (g * 4 + cb) ^ (r & 7);
            ushort8v v = *(const ushort8v*)&pool[r * 128 + pch * 8];
            *(ushort8v*)(base + r * 32 + cb * 8) = v;
        }
    } else if (outF32) {
        // Two COLUMN-half passes: stage 64x64 fp32 (16 KB) with +4r rotation,
        // then fully-coalesced float4 stores.
        float* poolF = (float*)pool;
        float* Df = (float*)D + (size_t)bz * sDb;
#pragma unroll
        for (int pass = 0; pass < 2; pass++) {
            __syncthreads();   // prior pool use (tiles / prev pass) complete
            if (wn == pass) {
#pragma unroll
                for (int i = 0; i < 2; i++) {
#pragma unroll
                    for (int j = 0; j < 4; j++) {
                        int c = j * 16 + lm;                     // 0..63 within half
                        #pragma unroll
                        for (int rg = 0; rg < 4; rg++) {
                            int r64 = wm * 32 + i * 16 + quad * 4 + rg;   // 0..63
                            float v = acc[i][j][rg] +
                                      bias[biasAlongM ? (m0 + r64) : (n0 + pass * 64 + c)];
                            int phys = (c + 4 * r64) & 63;       // rotation: bank spread
                            poolF[r64 * 64 + phys] = v;
                        }
                    }
                }
            }
            __syncthreads();
#pragma unroll
            for (int it = 0; it < 4; it++) {
                int id  = it * 256 + t;          // 0..1023
                int r64 = id >> 4;               // 0..63
                int c   = (id & 15) * 4;         // logical float4 col within half
                int phys = (c + 4 * r64) & 63;   // stays 16B-aligned, no wrap in 4
                float4v v = *(const float4v*)&poolF[r64 * 64 + phys];
                *(float4v*)&Df[(size_t)(m0 + r64) * ldd + n0 + pass * 64 + c] = v;
            }
        }
    } else {
        ushortT* Dh = (ushortT*)D + (size_t)bz * sDb;
#pragma unroll
        for (int i = 0; i < 2; i++) {
            int r0 = m0 + wm * 32 + i * 16 + quad * 4;
#pragma unroll
            for (int j = 0; j < 4; j++) {
                int c = n0 + wn * 64 + j * 16 + lm;
#pragma unroll
                for (int rg = 0; rg < 4; rg++) {
                    int r = r0 + rg;
                    float v = acc[i][j][rg] + bias[biasAlongM ? r : c];
                    Dh[(size_t)r * ldd + c] = f2bf(v);
                }
            }
        }
    }
}

// ---------------------------------------------------------------------------
// Multi-dilated 3x3 local attention, IN-PLACE on HEAD-MAJOR bf16 qkv:
// qkv[(part*8+hd)*32768 + bp][32], part in {q,k,v}.
// R10: block = one image row (64 px x 4 lanes/px, unchanged mapping) +
// LDS ROW-STAGING. The 18 scattered compute-phase global loads per thread
// (24 KB/block working set thrashing the 32 KB L1 at 8 blocks/CU) are
// replaced by: stage the 3 k-rows + 3 v-rows (4 KB each, 24 KB total) via
// global_load_lds (24 contiguous 1 KB wave-segments, 6 per wave), then
// ds_read_b128 in the compute phase. Global loads/thread: 19 -> 7.
// OOB rows are not staged (wave-uniform skip); vmask ensures their logit
// stays exactly 0 (in the softmax denominator) and v contributes nothing --
// numerics and accumulation order identical to R8. LDS 24 KB -> 6 blocks/CU.
// Quad-reduce via 2x __shfl_xor; softmax redundant in the 4 lanes; thread
// writes only its own q quarter -> race-free.
// ---------------------------------------------------------------------------
__global__ __launch_bounds__(256) void attn_k(ushortT* qkv) {
    __shared__ __align__(16) ushortT kls[6144];   // 3 rows x 64 px x 32 ch bf16
    __shared__ __align__(16) ushortT vls[6144];

    const int tid     = threadIdx.x;
    const int gt      = blockIdx.x * 256 + tid;
    const int quarter = gt & 3;          // channel quarter 0..3
    const int pix     = gt >> 2;         // 0..262143
    const int hd      = pix >> 15;       // 0..7  (block-uniform)
    const int rem     = pix & 32767;
    const int b       = rem >> 12;       // block-uniform
    const int p       = rem & 4095;      // block covers 64 consecutive p = one row
    const int h       = p >> 6;          // block-uniform
    const int w       = p & 63;
    const int dil     = (hd & 3) + 1;    // DILATIONS = [1,2,3,4]
    const int c0      = quarter * 8;

    const int wv   = tid >> 6;
    const int lane = tid & 63;

    ushortT*       qp    = qkv + ((size_t)hd * 32768 + (size_t)b * 4096 + p) * 32 + c0;
    const ushortT* kfull = qkv + ((size_t)(8  + hd) * 32768 + (size_t)b * 4096) * 32;
    const ushortT* vfull = qkv + ((size_t)(16 + hd) * 32768 + (size_t)b * 4096) * 32;

    // ---- stage: 24 segments of 1 KB (16B/lane); wave wv takes 6 ----
#pragma unroll
    for (int i = 0; i < 6; i++) {
        int s    = wv * 6 + i;            // 0..23
        int part = (s >= 12);             // 0 = k, 1 = v
        int r3   = (s % 12) >> 2;         // staged row 0..2
        int qs   = s & 3;                 // 1 KB quarter-segment within the row
        int hh   = h + (r3 - 1) * dil;    // block-uniform -> divergence-free skip
        if ((unsigned)hh < 64u) {
            const ushortT* src = (part ? vfull : kls == nullptr ? kfull : kfull)
                                 + (size_t)hh * 2048 + qs * 512 + lane * 8;
            if (part) src = vfull + (size_t)hh * 2048 + qs * 512 + lane * 8;
            ushortT* dst = (part ? vls : kls) + r3 * 2048 + qs * 512 + lane * 8;
            gld_lds16(src, dst);
        }
    }

    float q[8];
    {
        ushort8v v = *(const ushort8v*)qp;
#pragma unroll
        for (int j = 0; j < 8; j++) q[j] = bf2f(v[j]);
    }

    asm volatile("s_waitcnt vmcnt(0)" ::: "memory");
    __syncthreads();   // staged rows visible to all waves

    // ---- logits from LDS ----
    float lgt[9];
    unsigned vmask = 0;
#pragma unroll
    for (int ii = 0; ii < 3; ii++) {
#pragma unroll
        for (int jj = 0; jj < 3; jj++) {
            int idx = ii * 3 + jj;
            int hh = h + (ii - 1) * dil;   // block-uniform
            int ww = w + (jj - 1) * dil;   // group-uniform (same for the 4 lanes of a pixel)
            bool ok = ((unsigned)hh < 64u) && ((unsigned)ww < 64u);
            float l = 0.f;                 // OOB: logit exactly 0 (stays in denominator)
            if (ok) {
                vmask |= (1u << idx);
                ushort8v v = *(const ushort8v*)&kls[ii * 2048 + ww * 32 + c0];
#pragma unroll
                for (int j = 0; j < 8; j++) l += q[j] * bf2f(v[j]);
            }
            lgt[idx] = l;
        }
    }
    // quad reduce: lanes 4i..4i+3 hold partial dots of the same pixel.
    // OOB groups reduce 0+0+0+0 = 0 -> semantics preserved.
#pragma unroll
    for (int i = 0; i < 9; i++) {
        float l = lgt[i];
        l += __shfl_xor(l, 1);
        l += __shfl_xor(l, 2);
        lgt[i] = l * ATT_SCALE;
    }

    float mx = lgt[0];
#pragma unroll
    for (int i = 1; i < 9; i++) mx = fmaxf(mx, lgt[i]);
    float e[9], s = 0.f;
#pragma unroll
    for (int i = 0; i < 9; i++) { e[i] = __expf(lgt[i] - mx); s += e[i]; }
    const float inv = 1.f / s;

    // ---- PV from LDS ----
    float acc[8];
#pragma unroll
    for (int d = 0; d < 8; d++) acc[d] = 0.f;
#pragma unroll
    for (int ii = 0; ii < 3; ii++) {
#pragma unroll
        for (int jj = 0; jj < 3; jj++) {
            int idx = ii * 3 + jj;
            if ((vmask >> idx) & 1u) {    // OOB: v = 0, contributes nothing (e stays in s)
                int ww = w + (jj - 1) * dil;
                float pj = e[idx] * inv;
                ushort8v v = *(const ushort8v*)&vls[ii * 2048 + ww * 32 + c0];
#pragma unroll
                for (int j = 0; j < 8; j++) acc[j] += pj * bf2f(v[j]);
            }
        }
    }

    {
        ushort8v v;
#pragma unroll
        for (int j = 0; j < 8; j++) v[j] = f2bf(acc[j]);
        *(ushort8v*)qp = v;               // overwrite own q quarter
    }
}

// ---------------------------------------------------------------------------
extern "C" void kernel_launch(void* const* d_in, const int* in_sizes, int n_in,
                              void* d_out, int out_size, void* d_ws, size_t ws_size,
                              hipStream_t stream) {
    const float* x      = (const float*)d_in[0];  // (8,256,64,64) fp32
    const float* w_qkv  = (const float*)d_in[1];  // (768,256)
    const float* b_qkv  = (const float*)d_in[2];  // (768,)
    const float* w_proj = (const float*)d_in[3];  // (256,256)
    const float* b_proj = (const float*)d_in[4];  // (256,)

    // ws layout (256B-aligned): bqF | bpF | wqkvB | wprojB | qkv(head-major)
    char* ws = (char*)d_ws;
    float*   bqF    = (float*)(ws + 256);              // 768 f32
    float*   bpF    = (float*)(ws + 3328);             // 256 f32
    ushortT* wqkvB  = (ushortT*)(ws + 4352);           // 196608 bf16
    ushortT* wprojB = (ushortT*)(ws + 397568);         // 65536 bf16
    ushortT* qkv    = (ushortT*)(ws + 528640);         // 24 x 32768 x 32 bf16 = 48 MiB
    ushortT* xT     = (ushortT*)d_out;                 // (32768,256) bf16 scratch in d_out;
                                                       // fully overwritten by the final GEMM

    // 1) x (B,C,P) -> xT (B,P,C) bf16  +  folded param conversion
    transpose_cp<<<dim3(4, 64, 8), 256, 0, stream>>>(x, xT, w_qkv, w_proj, b_qkv, b_proj,
                                                     wqkvB, wprojB, bqF, bpF);

    // 2) qkv head-major = xT(32768,256) @ w_qkv^T + b_qkv   (bias along n)
    //    R8-exact: 64x128 tiles, 3072 blocks, ~6 resident/CU, swizzle 0.
    gemm_bt<<<dim3(3072), 256, 0, stream>>>(xT, wqkvB, 0, 256, 0,
                                            qkv, 0, 0, 1, 0,
                                            bqF, 0, 256, 0);

    // 3) attention in-place on head-major qkv (y overwrites q quarters)
    //    4096 blocks (one image row each), LDS row-staging (24 KB/block)
    attn_k<<<dim3(4096), 256, 0, stream>>>(qkv);

    // 4) out(b,256,4096) fp32 = w_proj @ y(b)^T + b_proj  (bias along m)
    //    R8-exact: 64x128 tiles, 1024 blocks, 4 resident/CU, swizzle 1.
    gemm_bt<<<dim3(1024), 256, 0, stream>>>(wprojB, qkv, (long long)4096 * 32, 0, 1,
                                            d_out, (long long)256 * 4096, 4096, 0, 1,
                                            bpF, 1, 256, 1);
}